// Round 6
// baseline (348.940 us; speedup 1.0000x reference)
//
#include <hip/hip_runtime.h>

// RGCN 2-layer, N=100000, E=3200000, R=8, H=C=16.
// Pipeline: fine histogram (dst>>6) -> scan -> 2-level radix partition by dst
// (coarse 49, fine 1563 buckets of 64 nodes) -> per-bucket layer blocks:
// block-local (node,rel) counting sort in LDS, then BIN-CONTIGUOUS register
// accumulation (relation constant per bin -> 1 add/edge, 8-deep gather ILP),
// scaled bf16 write to LDS S, then 4 rel-block MFMAs + root MFMA + fused
// relu / log_softmax. S stored bf16 -> 33 KB LDS -> 4 blocks/CU.

constexpr int NN = 100000;
constexpr int NE = 3200000;
constexpr int NFINE = 1563;    // ceil(NN/64)
constexpr int NCOARSE = 49;    // ceil(NN/2048)
constexpr int CAP = 3072;      // LDS edge capacity/bucket (mean 2048, sigma 45)

typedef short bf16x8 __attribute__((ext_vector_type(8)));
typedef short s16x4 __attribute__((ext_vector_type(4)));
typedef float f32x4 __attribute__((ext_vector_type(4)));

__device__ __forceinline__ short f2bf(float f) {
  union { float f; unsigned u; } v; v.f = f;
  unsigned r = v.u + 0x7FFFu + ((v.u >> 16) & 1u);  // RNE
  return (short)(r >> 16);
}
__device__ __forceinline__ float bf2f(unsigned short u) {
  union { unsigned u; float f; } v; v.u = ((unsigned)u) << 16; return v.f;
}

// K1: fine-bucket histogram (bucket = dst>>6), LDS-aggregated.
__global__ void __launch_bounds__(256) hist_kernel(
    const int* __restrict__ dst, unsigned* __restrict__ fcnt) {
  __shared__ unsigned h[NFINE];
  for (int i = threadIdx.x; i < NFINE; i += 256) h[i] = 0u;
  __syncthreads();
  const int base = blockIdx.x * 8192;
#pragma unroll
  for (int i = 0; i < 32; ++i) {
    int e = base + i * 256 + threadIdx.x;
    if (e < NE) atomicAdd(&h[(unsigned)dst[e] >> 6], 1u);
  }
  __syncthreads();
  for (int i = threadIdx.x; i < NFINE; i += 256)
    if (h[i]) atomicAdd(&fcnt[i], h[i]);
}

// K2: single-block exclusive scan of fcnt -> foff[0..NFINE], fine cursors,
// coarse boundaries and coarse cursors.
__global__ void __launch_bounds__(256) scan_kernel(
    const unsigned* __restrict__ fcnt, unsigned* __restrict__ foff,
    unsigned* __restrict__ fcur, unsigned* __restrict__ cbnd,
    unsigned* __restrict__ ccur) {
  __shared__ unsigned sh[256];
  unsigned v[7], s = 0;
#pragma unroll
  for (int j = 0; j < 7; ++j) {
    int idx = threadIdx.x * 7 + j;
    v[j] = (idx < NFINE) ? fcnt[idx] : 0u;
    s += v[j];
  }
  sh[threadIdx.x] = s;
  __syncthreads();
  for (int d = 1; d < 256; d <<= 1) {
    unsigned t = (threadIdx.x >= d) ? sh[threadIdx.x - d] : 0u;
    __syncthreads();
    sh[threadIdx.x] += t;
    __syncthreads();
  }
  unsigned run = sh[threadIdx.x] - s;
#pragma unroll
  for (int j = 0; j < 7; ++j) {
    int idx = threadIdx.x * 7 + j;
    if (idx <= NFINE) foff[idx] = run;
    if (idx < NFINE) fcur[idx] = run;
    run += v[j];
  }
  __syncthreads();
  if (threadIdx.x <= NCOARSE) {
    int f = threadIdx.x * 32; if (f > NFINE) f = NFINE;
    unsigned b = foff[f];
    cbnd[threadIdx.x] = b;
    if (threadIdx.x < NCOARSE) ccur[threadIdx.x] = b;
  }
}

// K3: coarse partition (dst>>11). Entry = src | rel<<17 | (dst&2047)<<20.
__global__ void __launch_bounds__(256) part1_kernel(
    const int* __restrict__ src, const int* __restrict__ dst,
    const int* __restrict__ typ, unsigned* __restrict__ ccur,
    unsigned* __restrict__ buf1) {
  __shared__ unsigned hist[NCOARSE];
  __shared__ unsigned gb[NCOARSE];
  if (threadIdx.x < NCOARSE) hist[threadIdx.x] = 0u;
  __syncthreads();
  const int base = blockIdx.x * 4096;
  unsigned ent[16], cb[16], rk[16];
#pragma unroll
  for (int i = 0; i < 16; ++i) {
    int e = base + i * 256 + threadIdx.x;
    if (e < NE) {
      unsigned d = (unsigned)dst[e];
      ent[i] = (unsigned)src[e] | ((unsigned)typ[e] << 17) | ((d & 2047u) << 20);
      cb[i] = d >> 11;
      rk[i] = atomicAdd(&hist[cb[i]], 1u);
    } else cb[i] = 0xFFFFFFFFu;
  }
  __syncthreads();
  if (threadIdx.x < NCOARSE && hist[threadIdx.x])
    gb[threadIdx.x] = atomicAdd(&ccur[threadIdx.x], hist[threadIdx.x]);
  __syncthreads();
#pragma unroll
  for (int i = 0; i < 16; ++i)
    if (cb[i] != 0xFFFFFFFFu) buf1[gb[cb[i]] + rk[i]] = ent[i];
}

// K4: fine partition within coarse segments. Final entry = low 26 bits.
__global__ void __launch_bounds__(256) part2_kernel(
    const unsigned* __restrict__ buf1, const unsigned* __restrict__ cbnd,
    unsigned* __restrict__ fcur, unsigned* __restrict__ buf2) {
  __shared__ unsigned hist[NFINE];
  __shared__ unsigned gb[NFINE];
  __shared__ unsigned cb_s[NCOARSE + 1];
  for (int i = threadIdx.x; i < NFINE; i += 256) hist[i] = 0u;
  if (threadIdx.x <= NCOARSE) cb_s[threadIdx.x] = cbnd[threadIdx.x];
  __syncthreads();
  const unsigned base = blockIdx.x * 4096u;
  int cc = 0;
  while (cc < NCOARSE - 1 && base >= cb_s[cc + 1]) ++cc;
  unsigned ent[16], fn[16], rk[16];
#pragma unroll
  for (int i = 0; i < 16; ++i) {
    unsigned p = base + i * 256u + threadIdx.x;
    if (p < (unsigned)NE) {
      unsigned e = buf1[p];
      while (p >= cb_s[cc + 1]) ++cc;
      fn[i] = (unsigned)cc * 32u + ((e >> 26) & 31u);
      ent[i] = e & 0x03FFFFFFu;
      rk[i] = atomicAdd(&hist[fn[i]], 1u);
    } else fn[i] = 0xFFFFFFFFu;
  }
  __syncthreads();
  for (int i = threadIdx.x; i < NFINE; i += 256)
    if (hist[i]) gb[i] = atomicAdd(&fcur[i], hist[i]);
  __syncthreads();
#pragma unroll
  for (int i = 0; i < 16; ++i)
    if (fn[i] != 0xFFFFFFFFu) buf2[gb[fn[i]] + rk[i]] = ent[i];
}

// K5/K6: per-bucket layer, 512 threads. Stage segment to regs + (node,rel)
// LDS histogram -> shfl wave-scan -> scatter to sorted LDS E -> bin-contiguous
// register accumulation (rel constant per bin; 1 add/edge, 8-deep gathers) ->
// scaled bf16 write to S -> MFMA transform + epilogue.
template <int MODE>
__global__ void __launch_bounds__(512) layer_kernel(
    const float* __restrict__ Xf, const unsigned short* __restrict__ Xh,
    const float* __restrict__ W, const float* __restrict__ ROOT,
    const float* __restrict__ BIAS, const unsigned* __restrict__ foff,
    const unsigned* __restrict__ buf2, unsigned short* __restrict__ Hout,
    float* __restrict__ Fout) {
  __shared__ unsigned short S[64 * 132];  // bf16 scaled sums, stride 132
  __shared__ unsigned E[CAP];             // sorted edge entries
  __shared__ unsigned cnt512[512];        // per-(node,rel) counts
  __shared__ unsigned cur512[512];        // excl-scan -> scatter ends
  __shared__ unsigned wsum[8];
  const int tid = threadIdx.x;

  cnt512[tid] = 0u;
  __syncthreads();

  const unsigned p0 = foff[blockIdx.x];
  const int seg = (int)(foff[blockIdx.x + 1] - p0);

  // Stage up to 6 entries/thread (3072 >= any bucket), histogram bins.
  unsigned e_0 = 0xFFFFFFFFu, e_1 = 0xFFFFFFFFu, e_2 = 0xFFFFFFFFu,
           e_3 = 0xFFFFFFFFu, e_4 = 0xFFFFFFFFu, e_5 = 0xFFFFFFFFu;
  if (tid < seg)          e_0 = buf2[p0 + tid];
  if (tid + 512 < seg)    e_1 = buf2[p0 + tid + 512];
  if (tid + 1024 < seg)   e_2 = buf2[p0 + tid + 1024];
  if (tid + 1536 < seg)   e_3 = buf2[p0 + tid + 1536];
  if (tid + 2048 < seg)   e_4 = buf2[p0 + tid + 2048];
  if (tid + 2560 < seg)   e_5 = buf2[p0 + tid + 2560];
  auto BIN = [](unsigned e) -> unsigned {
    return ((e >> 20) & 63u) * 8u + ((e >> 17) & 7u);
  };
  auto HB = [&](unsigned e) {
    if (e != 0xFFFFFFFFu) atomicAdd(&cnt512[BIN(e)], 1u);
  };
  HB(e_0); HB(e_1); HB(e_2); HB(e_3); HB(e_4); HB(e_5);
  __syncthreads();

  // Exclusive scan of cnt512: shfl wave-scan + cross-wave combine.
  unsigned own = cnt512[tid];
  unsigned incl = own;
#pragma unroll
  for (int d = 1; d < 64; d <<= 1) {
    unsigned t = __shfl_up(incl, d, 64);
    if ((tid & 63) >= d) incl += t;
  }
  if ((tid & 63) == 63) wsum[tid >> 6] = incl;
  __syncthreads();
  unsigned pre = 0;
#pragma unroll
  for (int wv = 0; wv < 8; ++wv)
    pre += (wv < (tid >> 6)) ? wsum[wv] : 0u;
  cur512[tid] = pre + incl - own;   // exclusive bin start
  __syncthreads();

  // Scatter into sorted E (cur512[b] becomes bin END afterwards).
  auto SC = [&](unsigned e) {
    if (e != 0xFFFFFFFFu) {
      unsigned pos = atomicAdd(&cur512[BIN(e)], 1u);
      if (pos < (unsigned)CAP) E[pos] = e;
    }
  };
  SC(e_0); SC(e_1); SC(e_2); SC(e_3); SC(e_4); SC(e_5);
  __syncthreads();

  // Bin-contiguous accumulation: 32 groups of 16 lanes; group gi owns nodes
  // gi*2, gi*2+1 (8 bins each). Lane = feature component c16.
  const int gi = tid >> 4;
  const int c16 = tid & 15;

  auto LDX = [&](unsigned e) -> float {
    unsigned sr = e & 0x1FFFFu;
    if (MODE) return bf2f(Xh[(size_t)sr * 16 + c16]);
    return Xf[(size_t)sr * 16 + c16];
  };

#pragma unroll
  for (int k = 0; k < 2; ++k) {
    const int nd = gi * 2 + k;
#pragma unroll
    for (int r = 0; r < 8; ++r) {
      const int bin = nd * 8 + r;
      const unsigned ct = cnt512[bin];
      int pe = (int)cur512[bin];
      int p = pe - (int)ct;
      float a0 = 0.f, a1 = 0.f, a2 = 0.f, a3 = 0.f,
            a4 = 0.f, a5 = 0.f, a6 = 0.f, a7 = 0.f;
      for (; p + 8 <= pe; p += 8) {
        unsigned f0 = E[p],     f1 = E[p + 1], f2 = E[p + 2], f3 = E[p + 3];
        unsigned f4 = E[p + 4], f5 = E[p + 5], f6 = E[p + 6], f7 = E[p + 7];
        float x0 = LDX(f0), x1 = LDX(f1), x2 = LDX(f2), x3 = LDX(f3);
        float x4 = LDX(f4), x5 = LDX(f5), x6 = LDX(f6), x7 = LDX(f7);
        a0 += x0; a1 += x1; a2 += x2; a3 += x3;
        a4 += x4; a5 += x5; a6 += x6; a7 += x7;
      }
      for (; p < pe; ++p) a0 += LDX(E[p]);
      float s = ((a0 + a1) + (a2 + a3)) + ((a4 + a5) + (a6 + a7));
      float iv = 1.f / (float)(ct ? ct : 1u);
      S[nd * 132 + r * 16 + c16] = (unsigned short)f2bf(s * iv);
    }
  }
  __syncthreads();

  // MFMA phase: waves 0..3 each own a 16-node tile.
  const int w = tid >> 6;
  if (w >= 4) return;
  const int lane = tid & 63;
  const int fc = lane & 15;
  const int g = lane >> 4;
  const int n0 = blockIdx.x * 64 + w * 16;

  bf16x8 b0, b1, b2, b3, brt;
#pragma unroll
  for (int j = 0; j < 8; ++j) {
    int kq = g * 8 + j; int rb = kq >> 4; int kk = kq & 15;
    b0[j] = f2bf(W[(rb + 0) * 256 + kk * 16 + fc]);
    b1[j] = f2bf(W[(rb + 2) * 256 + kk * 16 + fc]);
    b2[j] = f2bf(W[(rb + 4) * 256 + kk * 16 + fc]);
    b3[j] = f2bf(W[(rb + 6) * 256 + kk * 16 + fc]);
    brt[j] = (kq < 16) ? f2bf(ROOT[kq * 16 + fc]) : (short)0;
  }

  // A fragments: bf16 direct from S (8B-aligned s16x4 pairs, banks = 2*fc).
  const int kk0 = (g & 1) * 8;
  const int rsel = g >> 1;
  const int dl16 = w * 16 + fc;
  bf16x8 a0, a1, a2, a3;
#define LDA(AM, M)                                                        \
  {                                                                       \
    const unsigned short* sp2 = S + dl16 * 132 + (2 * (M) + rsel) * 16 + kk0; \
    s16x4 lo = *reinterpret_cast<const s16x4*>(sp2);                      \
    s16x4 hi = *reinterpret_cast<const s16x4*>(sp2 + 4);                  \
    AM[0] = lo[0]; AM[1] = lo[1]; AM[2] = lo[2]; AM[3] = lo[3];           \
    AM[4] = hi[0]; AM[5] = hi[1]; AM[6] = hi[2]; AM[7] = hi[3];           \
  }
  LDA(a0, 0) LDA(a1, 1) LDA(a2, 2) LDA(a3, 3)
#undef LDA

  bf16x8 ar = {0, 0, 0, 0, 0, 0, 0, 0};
  if (g < 2) {
    int node = n0 + fc;
    if (node < NN) {
      if (MODE == 0) {
        const float* xp = Xf + (size_t)node * 16 + g * 8;
        float4 pp = *reinterpret_cast<const float4*>(xp);
        float4 qq = *reinterpret_cast<const float4*>(xp + 4);
        ar[0] = f2bf(pp.x); ar[1] = f2bf(pp.y); ar[2] = f2bf(pp.z);
        ar[3] = f2bf(pp.w); ar[4] = f2bf(qq.x); ar[5] = f2bf(qq.y);
        ar[6] = f2bf(qq.z); ar[7] = f2bf(qq.w);
      } else {
        ar = *reinterpret_cast<const bf16x8*>(Xh + (size_t)node * 16 + g * 8);
      }
    }
  }

  const float bc = BIAS[fc];
  f32x4 acc = {bc, bc, bc, bc};
  acc = __builtin_amdgcn_mfma_f32_16x16x32_bf16(a0, b0, acc, 0, 0, 0);
  acc = __builtin_amdgcn_mfma_f32_16x16x32_bf16(a1, b1, acc, 0, 0, 0);
  acc = __builtin_amdgcn_mfma_f32_16x16x32_bf16(a2, b2, acc, 0, 0, 0);
  acc = __builtin_amdgcn_mfma_f32_16x16x32_bf16(a3, b3, acc, 0, 0, 0);
  acc = __builtin_amdgcn_mfma_f32_16x16x32_bf16(ar, brt, acc, 0, 0, 0);

  if (MODE == 0) {
#pragma unroll
    for (int r2 = 0; r2 < 4; ++r2) {
      int node = n0 + g * 4 + r2;
      if (node < NN)
        Hout[(size_t)node * 16 + fc] = (unsigned short)f2bf(fmaxf(acc[r2], 0.f));
    }
  } else {
#pragma unroll
    for (int r2 = 0; r2 < 4; ++r2) {
      int node = n0 + g * 4 + r2;
      float zv = acc[r2];
      float mx = zv;
      mx = fmaxf(mx, __shfl_xor(mx, 1));
      mx = fmaxf(mx, __shfl_xor(mx, 2));
      mx = fmaxf(mx, __shfl_xor(mx, 4));
      mx = fmaxf(mx, __shfl_xor(mx, 8));
      float sm = expf(zv - mx);
      sm += __shfl_xor(sm, 1);
      sm += __shfl_xor(sm, 2);
      sm += __shfl_xor(sm, 4);
      sm += __shfl_xor(sm, 8);
      if (node < NN)
        Fout[(size_t)node * 16 + fc] = zv - mx - logf(sm);
    }
  }
}

extern "C" void kernel_launch(void* const* d_in, const int* in_sizes, int n_in,
                              void* d_out, int out_size, void* d_ws, size_t ws_size,
                              hipStream_t stream) {
  const float* embed = (const float*)d_in[0];
  const float* W1    = (const float*)d_in[1];
  const float* root1 = (const float*)d_in[2];
  const float* b1    = (const float*)d_in[3];
  const float* W2    = (const float*)d_in[4];
  const float* root2 = (const float*)d_in[5];
  const float* b2    = (const float*)d_in[6];
  const int* eidx    = (const int*)d_in[7];
  const int* etyp    = (const int*)d_in[8];
  const int* src = eidx;
  const int* dst = eidx + NE;
  float* out = (float*)d_out;

  // ws (u32): fcnt[1600] foff[1600] fcur[1600] cbnd[64] ccur[64] buf1[NE] buf2[NE]
  // h (bf16, 3.2 MB) overlays buf1 (dead after part2).
  unsigned* fcnt = (unsigned*)d_ws;
  unsigned* foff = fcnt + 1600;
  unsigned* fcur = foff + 1600;
  unsigned* cbnd = fcur + 1600;
  unsigned* ccur = cbnd + 64;
  unsigned* buf1 = ccur + 64;
  unsigned* buf2 = buf1 + NE;
  unsigned short* h = (unsigned short*)buf1;

  hipMemsetAsync(fcnt, 0, 1600 * 4, stream);
  hist_kernel<<<391, 256, 0, stream>>>(dst, fcnt);
  scan_kernel<<<1, 256, 0, stream>>>(fcnt, foff, fcur, cbnd, ccur);
  part1_kernel<<<782, 256, 0, stream>>>(src, dst, etyp, ccur, buf1);
  part2_kernel<<<782, 256, 0, stream>>>(buf1, cbnd, fcur, buf2);
  layer_kernel<0><<<NFINE, 512, 0, stream>>>(embed, h, W1, root1, b1, foff,
                                             buf2, h, out);
  layer_kernel<1><<<NFINE, 512, 0, stream>>>(embed, h, W2, root2, b2, foff,
                                             buf2, h, out);
}

// Round 9
// 241.642 us; speedup vs baseline: 1.4440x; 1.4440x over previous
//
#include <hip/hip_runtime.h>

// RGCN 2-layer, N=100000, E=3200000, R=8, H=C=16.
// Pipeline: fine histogram (dst>>6) -> scan -> 2-level radix partition by dst
// (coarse 49, fine 1563 buckets of 64 nodes) -> embed->bf16 convert ->
// per-bucket layer blocks: block-local (node,rel) counting sort in LDS, then
// SEGMENTED-SUM VIA MFMA: per node-pair, batches of 32 edges, A = bin
// indicator matrix (bf16 0/1), B = gathered bf16 x rows -> D = per-(node,rel)
// sums. Scale by 1/cnt into bf16 S (stride 136 = 16B-aligned rows), then 4
// rel-block MFMAs + root MFMA + fused relu / log_softmax.
// All X gathers bf16 (3.2MB table, L2-resident).

constexpr int NN = 100000;
constexpr int NE = 3200000;
constexpr int NFINE = 1563;    // ceil(NN/64)
constexpr int NCOARSE = 49;    // ceil(NN/2048)
constexpr int CAP = 3072;      // LDS edge capacity/bucket (mean 2048, sigma 45)
constexpr int SST = 136;       // S node stride (ushorts); 136*2=272=16*17 -> 16B-aligned rows

typedef short bf16x8 __attribute__((ext_vector_type(8)));
typedef float f32x4 __attribute__((ext_vector_type(4)));

__device__ __forceinline__ short f2bf(float f) {
  union { float f; unsigned u; } v; v.f = f;
  unsigned r = v.u + 0x7FFFu + ((v.u >> 16) & 1u);  // RNE
  return (short)(r >> 16);
}

// K0: embed f32 -> bf16 table (once).
__global__ void __launch_bounds__(256) conv_kernel(
    const float* __restrict__ X, unsigned short* __restrict__ Xb) {
  int i = blockIdx.x * 256 + threadIdx.x;
  if (i < NN * 4) {   // groups of 4 floats
    float4 v = reinterpret_cast<const float4*>(X)[i];
    ushort4 o;
    o.x = (unsigned short)f2bf(v.x); o.y = (unsigned short)f2bf(v.y);
    o.z = (unsigned short)f2bf(v.z); o.w = (unsigned short)f2bf(v.w);
    reinterpret_cast<ushort4*>(Xb)[i] = o;
  }
}

// K1: fine-bucket histogram (bucket = dst>>6), LDS-aggregated.
__global__ void __launch_bounds__(256) hist_kernel(
    const int* __restrict__ dst, unsigned* __restrict__ fcnt) {
  __shared__ unsigned h[NFINE];
  for (int i = threadIdx.x; i < NFINE; i += 256) h[i] = 0u;
  __syncthreads();
  const int base = blockIdx.x * 8192;
#pragma unroll
  for (int i = 0; i < 32; ++i) {
    int e = base + i * 256 + threadIdx.x;
    if (e < NE) atomicAdd(&h[(unsigned)dst[e] >> 6], 1u);
  }
  __syncthreads();
  for (int i = threadIdx.x; i < NFINE; i += 256)
    if (h[i]) atomicAdd(&fcnt[i], h[i]);
}

// K2: single-block exclusive scan of fcnt -> foff[0..NFINE], fine cursors,
// coarse boundaries and coarse cursors.
__global__ void __launch_bounds__(256) scan_kernel(
    const unsigned* __restrict__ fcnt, unsigned* __restrict__ foff,
    unsigned* __restrict__ fcur, unsigned* __restrict__ cbnd,
    unsigned* __restrict__ ccur) {
  __shared__ unsigned sh[256];
  unsigned v[7], s = 0;
#pragma unroll
  for (int j = 0; j < 7; ++j) {
    int idx = threadIdx.x * 7 + j;
    v[j] = (idx < NFINE) ? fcnt[idx] : 0u;
    s += v[j];
  }
  sh[threadIdx.x] = s;
  __syncthreads();
  for (int d = 1; d < 256; d <<= 1) {
    unsigned t = (threadIdx.x >= d) ? sh[threadIdx.x - d] : 0u;
    __syncthreads();
    sh[threadIdx.x] += t;
    __syncthreads();
  }
  unsigned run = sh[threadIdx.x] - s;
#pragma unroll
  for (int j = 0; j < 7; ++j) {
    int idx = threadIdx.x * 7 + j;
    if (idx <= NFINE) foff[idx] = run;
    if (idx < NFINE) fcur[idx] = run;
    run += v[j];
  }
  __syncthreads();
  if (threadIdx.x <= NCOARSE) {
    int f = threadIdx.x * 32; if (f > NFINE) f = NFINE;
    unsigned b = foff[f];
    cbnd[threadIdx.x] = b;
    if (threadIdx.x < NCOARSE) ccur[threadIdx.x] = b;
  }
}

// K3: coarse partition (dst>>11). Entry = src | rel<<17 | (dst&2047)<<20.
__global__ void __launch_bounds__(256) part1_kernel(
    const int* __restrict__ src, const int* __restrict__ dst,
    const int* __restrict__ typ, unsigned* __restrict__ ccur,
    unsigned* __restrict__ buf1) {
  __shared__ unsigned hist[NCOARSE];
  __shared__ unsigned gb[NCOARSE];
  if (threadIdx.x < NCOARSE) hist[threadIdx.x] = 0u;
  __syncthreads();
  const int base = blockIdx.x * 4096;
  unsigned ent[16], cb[16], rk[16];
#pragma unroll
  for (int i = 0; i < 16; ++i) {
    int e = base + i * 256 + threadIdx.x;
    if (e < NE) {
      unsigned d = (unsigned)dst[e];
      ent[i] = (unsigned)src[e] | ((unsigned)typ[e] << 17) | ((d & 2047u) << 20);
      cb[i] = d >> 11;
      rk[i] = atomicAdd(&hist[cb[i]], 1u);
    } else cb[i] = 0xFFFFFFFFu;
  }
  __syncthreads();
  if (threadIdx.x < NCOARSE && hist[threadIdx.x])
    gb[threadIdx.x] = atomicAdd(&ccur[threadIdx.x], hist[threadIdx.x]);
  __syncthreads();
#pragma unroll
  for (int i = 0; i < 16; ++i)
    if (cb[i] != 0xFFFFFFFFu) buf1[gb[cb[i]] + rk[i]] = ent[i];
}

// K4: fine partition within coarse segments. Final entry = low 26 bits.
__global__ void __launch_bounds__(256) part2_kernel(
    const unsigned* __restrict__ buf1, const unsigned* __restrict__ cbnd,
    unsigned* __restrict__ fcur, unsigned* __restrict__ buf2) {
  __shared__ unsigned hist[NFINE];
  __shared__ unsigned gb[NFINE];
  __shared__ unsigned cb_s[NCOARSE + 1];
  for (int i = threadIdx.x; i < NFINE; i += 256) hist[i] = 0u;
  if (threadIdx.x <= NCOARSE) cb_s[threadIdx.x] = cbnd[threadIdx.x];
  __syncthreads();
  const unsigned base = blockIdx.x * 4096u;
  int cc = 0;
  while (cc < NCOARSE - 1 && base >= cb_s[cc + 1]) ++cc;
  unsigned ent[16], fn[16], rk[16];
#pragma unroll
  for (int i = 0; i < 16; ++i) {
    unsigned p = base + i * 256u + threadIdx.x;
    if (p < (unsigned)NE) {
      unsigned e = buf1[p];
      while (p >= cb_s[cc + 1]) ++cc;
      fn[i] = (unsigned)cc * 32u + ((e >> 26) & 31u);
      ent[i] = e & 0x03FFFFFFu;
      rk[i] = atomicAdd(&hist[fn[i]], 1u);
    } else fn[i] = 0xFFFFFFFFu;
  }
  __syncthreads();
  for (int i = threadIdx.x; i < NFINE; i += 256)
    if (hist[i]) gb[i] = atomicAdd(&fcur[i], hist[i]);
  __syncthreads();
#pragma unroll
  for (int i = 0; i < 16; ++i)
    if (fn[i] != 0xFFFFFFFFu) buf2[gb[fn[i]] + rk[i]] = ent[i];
}

// K5/K6: per-bucket layer, 512 threads. Phase A: stage+sort by (node,rel).
// Phase B: per node-pair (16 bins), batches of 32 edges -> one MFMA each:
// A = bin-indicator (bf16 0/1), B = gathered bf16 x -> D = segmented sums;
// scale by 1/cnt, write bf16 S. Phase C: 4 rel-block MFMAs + root + epilogue.
template <int MODE>
__global__ void __launch_bounds__(512) layer_kernel(
    const unsigned short* __restrict__ Xb, const float* __restrict__ W,
    const float* __restrict__ ROOT, const float* __restrict__ BIAS,
    const unsigned* __restrict__ foff, const unsigned* __restrict__ buf2,
    unsigned short* __restrict__ Hout, float* __restrict__ Fout) {
  __shared__ unsigned short S[64 * SST]; // bf16 scaled sums, 16B-aligned rows
  __shared__ unsigned E[CAP];            // sorted edge entries (zero-padded)
  __shared__ unsigned cnt512[512];       // per-(node,rel) counts
  __shared__ unsigned cur512[512];       // excl-scan -> bin ends
  __shared__ unsigned wsum[8];
  const int tid = threadIdx.x;

  cnt512[tid] = 0u;
  // Zero E so tail-batch reads of [seg, CAP) are defined (no 0*NaN in MFMA).
#pragma unroll
  for (int i = 0; i < CAP / 512; ++i) E[tid + i * 512] = 0u;
  __syncthreads();

  const unsigned p0 = foff[blockIdx.x];
  const int seg = (int)(foff[blockIdx.x + 1] - p0);

  // ---- Phase A: stage up to 6 entries/thread, histogram, scan, scatter ----
  unsigned e_0 = 0xFFFFFFFFu, e_1 = 0xFFFFFFFFu, e_2 = 0xFFFFFFFFu,
           e_3 = 0xFFFFFFFFu, e_4 = 0xFFFFFFFFu, e_5 = 0xFFFFFFFFu;
  if (tid < seg)          e_0 = buf2[p0 + tid];
  if (tid + 512 < seg)    e_1 = buf2[p0 + tid + 512];
  if (tid + 1024 < seg)   e_2 = buf2[p0 + tid + 1024];
  if (tid + 1536 < seg)   e_3 = buf2[p0 + tid + 1536];
  if (tid + 2048 < seg)   e_4 = buf2[p0 + tid + 2048];
  if (tid + 2560 < seg)   e_5 = buf2[p0 + tid + 2560];
  auto BIN = [](unsigned e) -> unsigned { return (e >> 17) & 511u; };
  auto HB = [&](unsigned e) {
    if (e != 0xFFFFFFFFu) atomicAdd(&cnt512[BIN(e)], 1u);
  };
  HB(e_0); HB(e_1); HB(e_2); HB(e_3); HB(e_4); HB(e_5);
  __syncthreads();

  unsigned own = cnt512[tid];
  unsigned incl = own;
#pragma unroll
  for (int d = 1; d < 64; d <<= 1) {
    unsigned t = __shfl_up(incl, d, 64);
    if ((tid & 63) >= d) incl += t;
  }
  if ((tid & 63) == 63) wsum[tid >> 6] = incl;
  __syncthreads();
  unsigned pre = 0;
#pragma unroll
  for (int wv = 0; wv < 8; ++wv)
    pre += (wv < (tid >> 6)) ? wsum[wv] : 0u;
  cur512[tid] = pre + incl - own;   // exclusive bin start
  __syncthreads();

  auto SC = [&](unsigned e) {
    if (e != 0xFFFFFFFFu) {
      unsigned pos = atomicAdd(&cur512[BIN(e)], 1u);
      if (pos < (unsigned)CAP) E[pos] = e;
    }
  };
  SC(e_0); SC(e_1); SC(e_2); SC(e_3); SC(e_4); SC(e_5);
  __syncthreads();
  // cur512[b] is now the END of bin b; start = cur512[b] - cnt512[b].

  // ---- Phase B: segmented sums via MFMA. Wave w owns pairs w*4..w*4+3. ----
  const int w = tid >> 6;
  const int lane = tid & 63;
  const int rc = lane & 15;     // A-row (local bin) == B-col (feature)
  const int quad = lane >> 4;

  for (int pq = 0; pq < 4; ++pq) {
    const int pp = w * 4 + pq;          // node pair 0..31
    const int pb = pp * 16;             // base bin
    const int beg = (int)(cur512[pb] - cnt512[pb]);
    const int end = (int)cur512[pb + 15];
    const unsigned rowbin = (unsigned)(pb + rc);

    f32x4 acc = {0.f, 0.f, 0.f, 0.f};
    int p = beg;
    for (; p + 32 <= end; p += 32) {    // full batches: no masking
      bf16x8 af, bv;
#pragma unroll
      for (int j = 0; j < 8; ++j) {
        unsigned e = E[p + quad * 8 + j];
        af[j] = (((e >> 17) & 511u) == rowbin) ? (short)0x3F80 : (short)0;
        bv[j] = (short)Xb[(size_t)(e & 0x1FFFFu) * 16 + rc];
      }
      acc = __builtin_amdgcn_mfma_f32_16x16x32_bf16(af, bv, acc, 0, 0, 0);
    }
    if (p < end) {                      // tail batch: mask invalid slots
      bf16x8 af, bv;
#pragma unroll
      for (int j = 0; j < 8; ++j) {
        int q = p + quad * 8 + j;
        unsigned e = E[q < CAP ? q : 0];  // E zero-padded -> defined reads
        bool v = q < end;
        af[j] = (v && ((e >> 17) & 511u) == rowbin) ? (short)0x3F80 : (short)0;
        bv[j] = (short)Xb[(size_t)(e & 0x1FFFFu) * 16 + rc];
      }
      acc = __builtin_amdgcn_mfma_f32_16x16x32_bf16(af, bv, acc, 0, 0, 0);
    }

    // D layout: col=rc (feature), row=quad*4+r2 (local bin). Scale + store.
#pragma unroll
    for (int r2 = 0; r2 < 4; ++r2) {
      int gbin = pb + quad * 4 + r2;
      unsigned ct = cnt512[gbin];
      float iv = 1.f / (float)(ct ? ct : 1u);
      int nd = gbin >> 3, rl = gbin & 7;
      S[nd * SST + rl * 16 + rc] = (unsigned short)f2bf(acc[r2] * iv);
    }
  }
  __syncthreads();

  // ---- Phase C: transform. Waves 0..3 each own a 16-node tile. ----
  if (w >= 4) return;
  const int fc = lane & 15;
  const int g = lane >> 4;
  const int n0 = blockIdx.x * 64 + w * 16;

  bf16x8 b0, b1, b2, b3, brt;
#pragma unroll
  for (int j = 0; j < 8; ++j) {
    int kq = g * 8 + j; int rb = kq >> 4; int kk = kq & 15;
    b0[j] = f2bf(W[(rb + 0) * 256 + kk * 16 + fc]);
    b1[j] = f2bf(W[(rb + 2) * 256 + kk * 16 + fc]);
    b2[j] = f2bf(W[(rb + 4) * 256 + kk * 16 + fc]);
    b3[j] = f2bf(W[(rb + 6) * 256 + kk * 16 + fc]);
    brt[j] = (kq < 16) ? f2bf(ROOT[kq * 16 + fc]) : (short)0;
  }

  // A fragments: 16B-aligned bf16x8 loads (SST*2 = 272 = 16*17).
  const int kk0 = (g & 1) * 8;
  const int rsel = g >> 1;
  const int dl16 = w * 16 + fc;
  bf16x8 a0, a1, a2, a3;
#define LDA(AM, M)                                                        \
  {                                                                       \
    const unsigned short* sp2 = S + dl16 * SST + (2 * (M) + rsel) * 16 + kk0; \
    AM = *reinterpret_cast<const bf16x8*>(sp2);                           \
  }
  LDA(a0, 0) LDA(a1, 1) LDA(a2, 2) LDA(a3, 3)
#undef LDA

  bf16x8 ar = {0, 0, 0, 0, 0, 0, 0, 0};
  if (g < 2) {
    int node = n0 + fc;
    if (node < NN)
      ar = *reinterpret_cast<const bf16x8*>(Xb + (size_t)node * 16 + g * 8);
  }

  const float bc = BIAS[fc];
  f32x4 acc = {bc, bc, bc, bc};
  acc = __builtin_amdgcn_mfma_f32_16x16x32_bf16(a0, b0, acc, 0, 0, 0);
  acc = __builtin_amdgcn_mfma_f32_16x16x32_bf16(a1, b1, acc, 0, 0, 0);
  acc = __builtin_amdgcn_mfma_f32_16x16x32_bf16(a2, b2, acc, 0, 0, 0);
  acc = __builtin_amdgcn_mfma_f32_16x16x32_bf16(a3, b3, acc, 0, 0, 0);
  acc = __builtin_amdgcn_mfma_f32_16x16x32_bf16(ar, brt, acc, 0, 0, 0);

  if (MODE == 0) {
#pragma unroll
    for (int r2 = 0; r2 < 4; ++r2) {
      int node = n0 + g * 4 + r2;
      if (node < NN)
        Hout[(size_t)node * 16 + fc] = (unsigned short)f2bf(fmaxf(acc[r2], 0.f));
    }
  } else {
#pragma unroll
    for (int r2 = 0; r2 < 4; ++r2) {
      int node = n0 + g * 4 + r2;
      float zv = acc[r2];
      float mx = zv;
      mx = fmaxf(mx, __shfl_xor(mx, 1));
      mx = fmaxf(mx, __shfl_xor(mx, 2));
      mx = fmaxf(mx, __shfl_xor(mx, 4));
      mx = fmaxf(mx, __shfl_xor(mx, 8));
      float sm = expf(zv - mx);
      sm += __shfl_xor(sm, 1);
      sm += __shfl_xor(sm, 2);
      sm += __shfl_xor(sm, 4);
      sm += __shfl_xor(sm, 8);
      if (node < NN)
        Fout[(size_t)node * 16 + fc] = zv - mx - logf(sm);
    }
  }
}

extern "C" void kernel_launch(void* const* d_in, const int* in_sizes, int n_in,
                              void* d_out, int out_size, void* d_ws, size_t ws_size,
                              hipStream_t stream) {
  const float* embed = (const float*)d_in[0];
  const float* W1    = (const float*)d_in[1];
  const float* root1 = (const float*)d_in[2];
  const float* b1    = (const float*)d_in[3];
  const float* W2    = (const float*)d_in[4];
  const float* root2 = (const float*)d_in[5];
  const float* b2    = (const float*)d_in[6];
  const int* eidx    = (const int*)d_in[7];
  const int* etyp    = (const int*)d_in[8];
  const int* src = eidx;
  const int* dst = eidx + NE;
  float* out = (float*)d_out;

  // ws (u32): fcnt[1600] foff[1600] fcur[1600] cbnd[64] ccur[64] buf1[NE] buf2[NE]
  // buf1 (dead after part2) hosts: h (bf16, first 800K u32) and xb (bf16
  // embed, next 800K u32); remaining 1.6M u32 is OOB-read spare.
  unsigned* fcnt = (unsigned*)d_ws;
  unsigned* foff = fcnt + 1600;
  unsigned* fcur = foff + 1600;
  unsigned* cbnd = fcur + 1600;
  unsigned* ccur = cbnd + 64;
  unsigned* buf1 = ccur + 64;
  unsigned* buf2 = buf1 + NE;
  unsigned short* h  = (unsigned short*)buf1;
  unsigned short* xb = (unsigned short*)(buf1 + 800000);

  hipMemsetAsync(fcnt, 0, 1600 * 4, stream);
  hist_kernel<<<391, 256, 0, stream>>>(dst, fcnt);
  scan_kernel<<<1, 256, 0, stream>>>(fcnt, foff, fcur, cbnd, ccur);
  part1_kernel<<<782, 256, 0, stream>>>(src, dst, etyp, ccur, buf1);
  part2_kernel<<<782, 256, 0, stream>>>(buf1, cbnd, fcur, buf2);
  conv_kernel<<<1563, 256, 0, stream>>>(embed, xb);   // after part2: buf1 dead
  layer_kernel<0><<<NFINE, 512, 0, stream>>>(xb, W1, root1, b1, foff,
                                             buf2, h, out);
  layer_kernel<1><<<NFINE, 512, 0, stream>>>(h, W2, root2, b2, foff,
                                             buf2, h, out);
}